// Round 1
// baseline (957.904 us; speedup 1.0000x reference)
//
#include <hip/hip_runtime.h>
#include <hip/hip_bf16.h>
#include <cstdint>

#define DI __device__ __forceinline__

typedef __attribute__((ext_vector_type(4))) float f32x4;
typedef __attribute__((ext_vector_type(8))) short s16x8;
typedef __attribute__((ext_vector_type(4))) short s16x4;

// Problem constants
constexpr int Sc = 2048;   // sequence
// B=4, D=1024, H=16, DK=64, M = B*S = 8192, BH = 64

DI short f2bf(float x) {
    __hip_bfloat16 h = __float2bfloat16(x);
    return __builtin_bit_cast(short, h);
}
DI float bf2f(short x) {
    __hip_bfloat16 h = __builtin_bit_cast(__hip_bfloat16, x);
    return __bfloat162float(h);
}

// ---- X [8192][1024] f32 -> X2 [8192][2048] bf16 : cols [0,1024)=hi, [1024,2048)=lo
__global__ void xconv_kernel(const float* __restrict__ X, short* __restrict__ X2) {
    size_t i = ((size_t)blockIdx.x * 256 + threadIdx.x) * 4;
    float4 v = *reinterpret_cast<const float4*>(X + i);
    int m = (int)(i >> 10);
    int k = (int)(i & 1023);
    float vv[4] = {v.x, v.y, v.z, v.w};
    short hi[4], lo[4];
#pragma unroll
    for (int j = 0; j < 4; ++j) { hi[j] = f2bf(vv[j]); lo[j] = f2bf(vv[j] - bf2f(hi[j])); }
    s16x4 h4 = {hi[0], hi[1], hi[2], hi[3]};
    s16x4 l4 = {lo[0], lo[1], lo[2], lo[3]};
    *reinterpret_cast<s16x4*>(X2 + (size_t)m * 2048 + k) = h4;
    *reinterpret_cast<s16x4*>(X2 + (size_t)m * 2048 + 1024 + k) = l4;
}

// ---- Wq/Wk/Wv [1024][1024] f32 -> WT2 [3072][2048] bf16 (transposed; [n][k]: hi at k, lo at 1024+k)
__global__ void wqkv_conv(const float* __restrict__ Wq, const float* __restrict__ Wk,
                          const float* __restrict__ Wv, short* __restrict__ WT2) {
    __shared__ float t[32][33];
    int z = blockIdx.z;
    const float* W = (z == 0) ? Wq : (z == 1 ? Wk : Wv);
    int k0 = blockIdx.x * 32, n0 = blockIdx.y * 32;
    int tx = threadIdx.x, ty = threadIdx.y;
#pragma unroll
    for (int i = 0; i < 4; ++i)
        t[ty + 8 * i][tx] = W[(size_t)(k0 + ty + 8 * i) * 1024 + n0 + tx];
    __syncthreads();
#pragma unroll
    for (int i = 0; i < 4; ++i) {
        float v = t[tx][ty + 8 * i];
        short hi = f2bf(v), lo = f2bf(v - bf2f(hi));
        size_t r = (size_t)(z * 1024 + n0 + ty + 8 * i) * 2048 + k0 + tx;
        WT2[r] = hi;
        WT2[r + 1024] = lo;
    }
}

// ---- Wo [1024][1024] f32 -> WoT [1024][1024] bf16 (transposed, hi only)
__global__ void wo_conv(const float* __restrict__ Wo, short* __restrict__ WoT) {
    __shared__ float t[32][33];
    int k0 = blockIdx.x * 32, n0 = blockIdx.y * 32;
    int tx = threadIdx.x, ty = threadIdx.y;
#pragma unroll
    for (int i = 0; i < 4; ++i)
        t[ty + 8 * i][tx] = Wo[(size_t)(k0 + ty + 8 * i) * 1024 + n0 + tx];
    __syncthreads();
#pragma unroll
    for (int i = 0; i < 4; ++i)
        WoT[(size_t)(n0 + ty + 8 * i) * 1024 + k0 + tx] = f2bf(t[tx][ty + 8 * i]);
}

// ---- bias table [16][4096]: tab[h][delta+2047] = rel_bias[bucket(delta)][h]
// Exact integer thresholds equivalent to int(log(rel/8)/log(16)*8) under correctly-rounded log.
__global__ void bias_kernel(const float* __restrict__ rel_bias, float* __restrict__ tab) {
    int idx = blockIdx.x * 256 + threadIdx.x;  // 16*4096
    int h = idx >> 12;
    int i = idx & 4095;
    int delta = i - 2047;
    int ad = delta < 0 ? -delta : delta;
    int b;
    if (ad < 8) b = ad;
    else if (ad < 12) b = 8;
    else if (ad < 16) b = 9;
    else if (ad < 23) b = 10;
    else if (ad < 32) b = 11;
    else if (ad < 46) b = 12;
    else if (ad < 64) b = 13;
    else if (ad < 91) b = 14;
    else b = 15;
    if (delta > 0) b += 16;
    tab[idx] = rel_bias[b * 16 + h];
}

// ---- GEMM: C[M,N] = A[M,K'] * B[K',N], B given as B^T [N][K'] bf16.
// Split-K' remap: colA = kk - (kk>=aWrap ? aWrap : 0), same for B (folds hi/lo duplication).
// EPI=0: store fp32 C. EPI=1 (QKV): split-write Q'/K' (hi|lo) and V^T bf16.
template <int EPI>
__launch_bounds__(256)
__global__ void gemm_bt(const short* __restrict__ A, const short* __restrict__ Bt,
                        int K, int lda, int ldb, int aWrap, int bWrap,
                        float* __restrict__ C, int ldc,
                        short* __restrict__ q2, short* __restrict__ k2, short* __restrict__ vt) {
    __shared__ __align__(16) short As[128 * 32];
    __shared__ __align__(16) short Bs[128 * 32];
    const int tid = threadIdx.x;
    const int w = tid >> 6, l = tid & 63;
    const int m0 = blockIdx.x * 128, n0 = blockIdx.y * 128;
    const int wm = (w >> 1) * 64, wn = (w & 1) * 64;
    const int ar = tid >> 2, ac = (tid & 3) * 8;

    f32x4 acc[4][4];
#pragma unroll
    for (int i = 0; i < 4; ++i)
#pragma unroll
        for (int j = 0; j < 4; ++j) acc[i][j] = (f32x4){0.f, 0.f, 0.f, 0.f};

    const int nk = K / 32;
    s16x8 a0, a1, b0, b1;
    auto ldtile = [&](int kt) {
        int kk = kt * 32;
        int ca = kk - (kk >= aWrap ? aWrap : 0);
        int cb = kk - (kk >= bWrap ? bWrap : 0);
        a0 = *reinterpret_cast<const s16x8*>(A + (size_t)(m0 + ar) * lda + ca + ac);
        a1 = *reinterpret_cast<const s16x8*>(A + (size_t)(m0 + 64 + ar) * lda + ca + ac);
        b0 = *reinterpret_cast<const s16x8*>(Bt + (size_t)(n0 + ar) * ldb + cb + ac);
        b1 = *reinterpret_cast<const s16x8*>(Bt + (size_t)(n0 + 64 + ar) * ldb + cb + ac);
    };
    ldtile(0);
    for (int kt = 0; kt < nk; ++kt) {
        __syncthreads();
        *reinterpret_cast<s16x8*>(As + ar * 32 + ac) = a0;
        *reinterpret_cast<s16x8*>(As + (64 + ar) * 32 + ac) = a1;
        *reinterpret_cast<s16x8*>(Bs + ar * 32 + ac) = b0;
        *reinterpret_cast<s16x8*>(Bs + (64 + ar) * 32 + ac) = b1;
        __syncthreads();
        if (kt + 1 < nk) ldtile(kt + 1);
        s16x8 af[4], bfv[4];
#pragma unroll
        for (int i = 0; i < 4; ++i)
            af[i] = *reinterpret_cast<const s16x8*>(As + (wm + i * 16 + (l & 15)) * 32 + (l >> 4) * 8);
#pragma unroll
        for (int i = 0; i < 4; ++i)
            bfv[i] = *reinterpret_cast<const s16x8*>(Bs + (wn + i * 16 + (l & 15)) * 32 + (l >> 4) * 8);
#pragma unroll
        for (int mi = 0; mi < 4; ++mi)
#pragma unroll
            for (int ni = 0; ni < 4; ++ni)
                acc[mi][ni] = __builtin_amdgcn_mfma_f32_16x16x32_bf16(af[mi], bfv[ni], acc[mi][ni], 0, 0, 0);
    }

    const int rl = l >> 4, cl = l & 15;
    if (EPI == 0) {
#pragma unroll
        for (int mi = 0; mi < 4; ++mi) {
            int row = m0 + wm + mi * 16 + rl * 4;
#pragma unroll
            for (int ni = 0; ni < 4; ++ni) {
                int col = n0 + wn + ni * 16 + cl;
#pragma unroll
                for (int r = 0; r < 4; ++r)
                    C[(size_t)(row + r) * ldc + col] = acc[mi][ni][r];
            }
        }
    } else {
        int region = n0 >> 10;  // block-uniform: 0=Q 1=K 2=V
#pragma unroll
        for (int mi = 0; mi < 4; ++mi) {
#pragma unroll
            for (int ni = 0; ni < 4; ++ni) {
#pragma unroll
                for (int r = 0; r < 4; ++r) {
                    int m = m0 + wm + mi * 16 + rl * 4 + r;
                    int n = (n0 & 1023) + wn + ni * 16 + cl;
                    int bb = m >> 11, s = m & 2047;
                    int h = n >> 6, d = n & 63;
                    int bh = bb * 16 + h;
                    float c = acc[mi][ni][r];
                    short hi = f2bf(c);
                    if (region == 0) {
                        short lo = f2bf(c - bf2f(hi));
                        size_t base = ((size_t)bh * 2048 + s) * 128;
                        q2[base + d] = hi;
                        q2[base + 64 + d] = lo;
                    } else if (region == 1) {
                        short lo = f2bf(c - bf2f(hi));
                        size_t base = ((size_t)bh * 2048 + s) * 128;
                        k2[base + d] = hi;
                        k2[base + 64 + d] = lo;
                    } else {
                        vt[((size_t)bh * 64 + d) * 2048 + s] = hi;
                    }
                }
            }
        }
    }
}

// ---- Flash attention: grid (S/64, BH), 256 threads = 4 waves, each wave owns 16 q-rows.
// Q',K' = [bh][s][128] bf16 (hi d0..63 | lo d64..127). V^T = [bh][d][s] bf16.
// Scores via split QK^T (6 MFMAs / 16x16 tile): hi*hi + hi*lo + lo*hi. Online softmax; P->LDS->PV.
__launch_bounds__(256)
__global__ void flash_kernel(const short* __restrict__ q2, const short* __restrict__ k2,
                             const short* __restrict__ vt, const float* __restrict__ btab,
                             short* __restrict__ attnb) {
    __shared__ __align__(16) short pbuf[2][4][16 * 40];  // double-buffered, stride 40 to cut bank conflicts
    const int tid = threadIdx.x;
    const int w = tid >> 6, l = tid & 63;
    const int rl = l >> 4, cl = l & 15;
    const int bh = blockIdx.y;
    const int h = bh & 15;
    const int q0 = blockIdx.x * 64 + w * 16;

    const short* Q = q2 + (size_t)bh * Sc * 128;
    const short* Kp = k2 + (size_t)bh * Sc * 128;
    const short* V = vt + (size_t)bh * 64 * Sc;
    const float* bt = btab + h * 4096;

    s16x8 qf[4];
#pragma unroll
    for (int sg = 0; sg < 2; ++sg)
#pragma unroll
        for (int a = 0; a < 2; ++a)
            qf[sg * 2 + a] =
                *reinterpret_cast<const s16x8*>(Q + (size_t)(q0 + cl) * 128 + sg * 64 + a * 32 + rl * 8);

    f32x4 acc[4];
#pragma unroll
    for (int i = 0; i < 4; ++i) acc[i] = (f32x4){0.f, 0.f, 0.f, 0.f};
    float mrow[4] = {-1e30f, -1e30f, -1e30f, -1e30f};
    float lrow[4] = {0.f, 0.f, 0.f, 0.f};

    for (int it = 0; it < 64; ++it) {
        int kv0 = it * 32;
        f32x4 sc[2];
#pragma unroll
        for (int t = 0; t < 2; ++t) {
            sc[t] = (f32x4){0.f, 0.f, 0.f, 0.f};
            s16x8 kf[4];
#pragma unroll
            for (int sg = 0; sg < 2; ++sg)
#pragma unroll
                for (int a = 0; a < 2; ++a)
                    kf[sg * 2 + a] = *reinterpret_cast<const s16x8*>(
                        Kp + (size_t)(kv0 + t * 16 + cl) * 128 + sg * 64 + a * 32 + rl * 8);
            sc[t] = __builtin_amdgcn_mfma_f32_16x16x32_bf16(qf[0], kf[0], sc[t], 0, 0, 0);
            sc[t] = __builtin_amdgcn_mfma_f32_16x16x32_bf16(qf[1], kf[1], sc[t], 0, 0, 0);
            sc[t] = __builtin_amdgcn_mfma_f32_16x16x32_bf16(qf[0], kf[2], sc[t], 0, 0, 0);
            sc[t] = __builtin_amdgcn_mfma_f32_16x16x32_bf16(qf[1], kf[3], sc[t], 0, 0, 0);
            sc[t] = __builtin_amdgcn_mfma_f32_16x16x32_bf16(qf[2], kf[0], sc[t], 0, 0, 0);
            sc[t] = __builtin_amdgcn_mfma_f32_16x16x32_bf16(qf[3], kf[1], sc[t], 0, 0, 0);
            int col = kv0 + t * 16 + cl;
#pragma unroll
            for (int r = 0; r < 4; ++r) {
                int row = q0 + rl * 4 + r;
                sc[t][r] += bt[col - row + 2047];
            }
        }
        float tm[4], al[4], pr[2][4], rs[4];
#pragma unroll
        for (int r = 0; r < 4; ++r) tm[r] = fmaxf(sc[0][r], sc[1][r]);
#pragma unroll
        for (int off = 1; off < 16; off <<= 1)
#pragma unroll
            for (int r = 0; r < 4; ++r) tm[r] = fmaxf(tm[r], __shfl_xor(tm[r], off));
#pragma unroll
        for (int r = 0; r < 4; ++r) {
            float mn = fmaxf(mrow[r], tm[r]);
            al[r] = __expf(mrow[r] - mn);
            mrow[r] = mn;
            pr[0][r] = __expf(sc[0][r] - mn);
            pr[1][r] = __expf(sc[1][r] - mn);
            rs[r] = pr[0][r] + pr[1][r];
        }
#pragma unroll
        for (int off = 1; off < 16; off <<= 1)
#pragma unroll
            for (int r = 0; r < 4; ++r) rs[r] += __shfl_xor(rs[r], off);
#pragma unroll
        for (int r = 0; r < 4; ++r) lrow[r] = lrow[r] * al[r] + rs[r];
#pragma unroll
        for (int i = 0; i < 4; ++i) {
            f32x4 t4 = acc[i];
#pragma unroll
            for (int r = 0; r < 4; ++r) t4[r] *= al[r];
            acc[i] = t4;
        }
        short* pl = &pbuf[it & 1][w][0];
#pragma unroll
        for (int t = 0; t < 2; ++t)
#pragma unroll
            for (int r = 0; r < 4; ++r)
                pl[(rl * 4 + r) * 40 + t * 16 + cl] = f2bf(pr[t][r]);
        __syncthreads();
        s16x8 pf = *reinterpret_cast<const s16x8*>(pl + cl * 40 + rl * 8);
#pragma unroll
        for (int dt = 0; dt < 4; ++dt) {
            s16x8 vf = *reinterpret_cast<const s16x8*>(V + (size_t)(dt * 16 + cl) * Sc + kv0 + rl * 8);
            acc[dt] = __builtin_amdgcn_mfma_f32_16x16x32_bf16(pf, vf, acc[dt], 0, 0, 0);
        }
    }

    int bb = bh >> 4;
#pragma unroll
    for (int dt = 0; dt < 4; ++dt)
#pragma unroll
        for (int r = 0; r < 4; ++r) {
            int q = q0 + rl * 4 + r;
            float o = acc[dt][r] / lrow[r];
            attnb[((size_t)(bb * 2048 + q)) * 1024 + h * 64 + dt * 16 + cl] = f2bf(o);
        }
}

extern "C" void kernel_launch(void* const* d_in, const int* in_sizes, int n_in,
                              void* d_out, int out_size, void* d_ws, size_t ws_size,
                              hipStream_t stream) {
    const float* X = (const float*)d_in[0];
    const float* Wq = (const float*)d_in[1];
    const float* Wk = (const float*)d_in[2];
    const float* Wv = (const float*)d_in[3];
    const float* Wo = (const float*)d_in[4];
    const float* RB = (const float*)d_in[5];

    // Workspace layout (~149.2 MB total)
    char* ws = (char*)d_ws;
    size_t off = 0;
    auto alloc = [&](size_t bytes) {
        void* p = ws + off;
        off += (bytes + 255) & ~(size_t)255;
        return p;
    };
    short* X2 = (short*)alloc((size_t)8192 * 2048 * 2);    // X hi|lo
    short* WT2 = (short*)alloc((size_t)3072 * 2048 * 2);   // [Wq;Wk;Wv]^T hi|lo
    short* q2 = (short*)alloc((size_t)64 * 2048 * 128 * 2);  // Q' hi|lo
    short* k2 = (short*)alloc((size_t)64 * 2048 * 128 * 2);  // K' hi|lo
    short* vt = (short*)alloc((size_t)64 * 64 * 2048 * 2);   // V^T
    short* attn = (short*)alloc((size_t)8192 * 1024 * 2);    // attention output bf16
    short* WoT = (short*)alloc((size_t)1024 * 1024 * 2);     // Wo^T
    float* btab = (float*)alloc((size_t)16 * 4096 * 4);      // bias table

    xconv_kernel<<<8192, 256, 0, stream>>>(X, X2);
    wqkv_conv<<<dim3(32, 32, 3), dim3(32, 8), 0, stream>>>(Wq, Wk, Wv, WT2);
    wo_conv<<<dim3(32, 32), dim3(32, 8), 0, stream>>>(Wo, WoT);
    bias_kernel<<<256, 256, 0, stream>>>(RB, btab);
    // QKV projection: A=[Xhi|Xhi|Xlo] via aWrap, B=[Whi|Wlo|Whi] via bWrap, K'=3072
    gemm_bt<1><<<dim3(64, 24), 256, 0, stream>>>(X2, WT2, 3072, 2048, 2048, 1024, 2048,
                                                 nullptr, 0, q2, k2, vt);
    flash_kernel<<<dim3(32, 64), 256, 0, stream>>>(q2, k2, vt, btab, attn);
    // Output projection (single bf16)
    gemm_bt<0><<<dim3(64, 8), 256, 0, stream>>>(attn, WoT, 1024, 1024, 1024, 1 << 30, 1 << 30,
                                                (float*)d_out, 1024, nullptr, nullptr, nullptr);
}

// Round 2
// 633.396 us; speedup vs baseline: 1.5123x; 1.5123x over previous
//
#include <hip/hip_runtime.h>
#include <hip/hip_bf16.h>
#include <cstdint>

#define DI __device__ __forceinline__

typedef __attribute__((ext_vector_type(4))) float f32x4;
typedef __attribute__((ext_vector_type(8))) short s16x8;
typedef __attribute__((ext_vector_type(4))) short s16x4;
typedef unsigned int u32;

// Problem constants
constexpr int Sc = 2048;   // sequence
// B=4, D=1024, H=16, DK=64, M = B*S = 8192, BH = 64

DI short f2bf(float x) {
    __hip_bfloat16 h = __float2bfloat16(x);
    return __builtin_bit_cast(short, h);
}
DI float bf2f(short x) {
    __hip_bfloat16 h = __builtin_bit_cast(__hip_bfloat16, x);
    return __bfloat162float(h);
}

// async 16B global -> LDS (dest = wave-uniform base + lane*16)
DI void cp16(const short* g, short* l) {
    __builtin_amdgcn_global_load_lds(
        (const __attribute__((address_space(1))) u32*)g,
        (__attribute__((address_space(3))) u32*)l, 16, 0, 0);
}

// ---- X [8192][1024] f32 -> X2 [8192][2048] bf16 : cols [0,1024)=hi, [1024,2048)=lo
__global__ void xconv_kernel(const float* __restrict__ X, short* __restrict__ X2) {
    size_t i = ((size_t)blockIdx.x * 256 + threadIdx.x) * 4;
    float4 v = *reinterpret_cast<const float4*>(X + i);
    int m = (int)(i >> 10);
    int k = (int)(i & 1023);
    float vv[4] = {v.x, v.y, v.z, v.w};
    short hi[4], lo[4];
#pragma unroll
    for (int j = 0; j < 4; ++j) { hi[j] = f2bf(vv[j]); lo[j] = f2bf(vv[j] - bf2f(hi[j])); }
    s16x4 h4 = {hi[0], hi[1], hi[2], hi[3]};
    s16x4 l4 = {lo[0], lo[1], lo[2], lo[3]};
    *reinterpret_cast<s16x4*>(X2 + (size_t)m * 2048 + k) = h4;
    *reinterpret_cast<s16x4*>(X2 + (size_t)m * 2048 + 1024 + k) = l4;
}

// ---- Wq/Wk/Wv [1024][1024] f32 -> WT2 [3072][2048] bf16 (transposed; [n][k]: hi at k, lo at 1024+k)
__global__ void wqkv_conv(const float* __restrict__ Wq, const float* __restrict__ Wk,
                          const float* __restrict__ Wv, short* __restrict__ WT2) {
    __shared__ float t[32][33];
    int z = blockIdx.z;
    const float* W = (z == 0) ? Wq : (z == 1 ? Wk : Wv);
    int k0 = blockIdx.x * 32, n0 = blockIdx.y * 32;
    int tx = threadIdx.x, ty = threadIdx.y;
#pragma unroll
    for (int i = 0; i < 4; ++i)
        t[ty + 8 * i][tx] = W[(size_t)(k0 + ty + 8 * i) * 1024 + n0 + tx];
    __syncthreads();
#pragma unroll
    for (int i = 0; i < 4; ++i) {
        float v = t[tx][ty + 8 * i];
        short hi = f2bf(v), lo = f2bf(v - bf2f(hi));
        size_t r = (size_t)(z * 1024 + n0 + ty + 8 * i) * 2048 + k0 + tx;
        WT2[r] = hi;
        WT2[r + 1024] = lo;
    }
}

// ---- Wo [1024][1024] f32 -> WoT [1024][1024] bf16 (transposed, hi only)
__global__ void wo_conv(const float* __restrict__ Wo, short* __restrict__ WoT) {
    __shared__ float t[32][33];
    int k0 = blockIdx.x * 32, n0 = blockIdx.y * 32;
    int tx = threadIdx.x, ty = threadIdx.y;
#pragma unroll
    for (int i = 0; i < 4; ++i)
        t[ty + 8 * i][tx] = Wo[(size_t)(k0 + ty + 8 * i) * 1024 + n0 + tx];
    __syncthreads();
#pragma unroll
    for (int i = 0; i < 4; ++i)
        WoT[(size_t)(n0 + ty + 8 * i) * 1024 + k0 + tx] = f2bf(t[tx][ty + 8 * i]);
}

// ---- bias table [16][4096] bf16: tab[h][delta+2047] = rel_bias[bucket(delta)][h]
// Exact integer thresholds equivalent to int(log(rel/8)/log(16)*8) under correctly-rounded log.
__global__ void bias_kernel(const float* __restrict__ rel_bias, short* __restrict__ tab) {
    int idx = blockIdx.x * 256 + threadIdx.x;  // 16*4096
    int h = idx >> 12;
    int i = idx & 4095;
    int delta = i - 2047;
    int ad = delta < 0 ? -delta : delta;
    int b;
    if (ad < 8) b = ad;
    else if (ad < 12) b = 8;
    else if (ad < 16) b = 9;
    else if (ad < 23) b = 10;
    else if (ad < 32) b = 11;
    else if (ad < 46) b = 12;
    else if (ad < 64) b = 13;
    else if (ad < 91) b = 14;
    else b = 15;
    if (delta > 0) b += 16;
    tab[idx] = f2bf(rel_bias[b * 16 + h]);
}

// ---- GEMM: C[M,N] = A[M,K'] * B[K',N], B given as B^T [N][K'] bf16.
// Split-K' remap: colA = kk - (kk>=aWrap ? aWrap : 0), same for B (folds hi/lo duplication).
// EPI=0: store fp32 C. EPI=1 (QKV): split-write Q'/K' (hi|lo) and V^T bf16.
template <int EPI>
__launch_bounds__(256)
__global__ void gemm_bt(const short* __restrict__ A, const short* __restrict__ Bt,
                        int K, int lda, int ldb, int aWrap, int bWrap,
                        float* __restrict__ C, int ldc,
                        short* __restrict__ q2, short* __restrict__ k2, short* __restrict__ vt) {
    __shared__ __align__(16) short As[128 * 32];
    __shared__ __align__(16) short Bs[128 * 32];
    const int tid = threadIdx.x;
    const int w = tid >> 6, l = tid & 63;
    const int m0 = blockIdx.x * 128, n0 = blockIdx.y * 128;
    const int wm = (w >> 1) * 64, wn = (w & 1) * 64;
    const int ar = tid >> 2, ac = (tid & 3) * 8;

    f32x4 acc[4][4];
#pragma unroll
    for (int i = 0; i < 4; ++i)
#pragma unroll
        for (int j = 0; j < 4; ++j) acc[i][j] = (f32x4){0.f, 0.f, 0.f, 0.f};

    const int nk = K / 32;
    s16x8 a0, a1, b0, b1;
    auto ldtile = [&](int kt) {
        int kk = kt * 32;
        int ca = kk - (kk >= aWrap ? aWrap : 0);
        int cb = kk - (kk >= bWrap ? bWrap : 0);
        a0 = *reinterpret_cast<const s16x8*>(A + (size_t)(m0 + ar) * lda + ca + ac);
        a1 = *reinterpret_cast<const s16x8*>(A + (size_t)(m0 + 64 + ar) * lda + ca + ac);
        b0 = *reinterpret_cast<const s16x8*>(Bt + (size_t)(n0 + ar) * ldb + cb + ac);
        b1 = *reinterpret_cast<const s16x8*>(Bt + (size_t)(n0 + 64 + ar) * ldb + cb + ac);
    };
    ldtile(0);
    for (int kt = 0; kt < nk; ++kt) {
        __syncthreads();
        *reinterpret_cast<s16x8*>(As + ar * 32 + ac) = a0;
        *reinterpret_cast<s16x8*>(As + (64 + ar) * 32 + ac) = a1;
        *reinterpret_cast<s16x8*>(Bs + ar * 32 + ac) = b0;
        *reinterpret_cast<s16x8*>(Bs + (64 + ar) * 32 + ac) = b1;
        __syncthreads();
        if (kt + 1 < nk) ldtile(kt + 1);
        s16x8 af[4], bfv[4];
#pragma unroll
        for (int i = 0; i < 4; ++i)
            af[i] = *reinterpret_cast<const s16x8*>(As + (wm + i * 16 + (l & 15)) * 32 + (l >> 4) * 8);
#pragma unroll
        for (int i = 0; i < 4; ++i)
            bfv[i] = *reinterpret_cast<const s16x8*>(Bs + (wn + i * 16 + (l & 15)) * 32 + (l >> 4) * 8);
#pragma unroll
        for (int mi = 0; mi < 4; ++mi)
#pragma unroll
            for (int ni = 0; ni < 4; ++ni)
                acc[mi][ni] = __builtin_amdgcn_mfma_f32_16x16x32_bf16(af[mi], bfv[ni], acc[mi][ni], 0, 0, 0);
    }

    const int rl = l >> 4, cl = l & 15;
    if (EPI == 0) {
#pragma unroll
        for (int mi = 0; mi < 4; ++mi) {
            int row = m0 + wm + mi * 16 + rl * 4;
#pragma unroll
            for (int ni = 0; ni < 4; ++ni) {
                int col = n0 + wn + ni * 16 + cl;
#pragma unroll
                for (int r = 0; r < 4; ++r)
                    C[(size_t)(row + r) * ldc + col] = acc[mi][ni][r];
            }
        }
    } else {
        int region = n0 >> 10;  // block-uniform: 0=Q 1=K 2=V
#pragma unroll
        for (int mi = 0; mi < 4; ++mi) {
#pragma unroll
            for (int ni = 0; ni < 4; ++ni) {
#pragma unroll
                for (int r = 0; r < 4; ++r) {
                    int m = m0 + wm + mi * 16 + rl * 4 + r;
                    int n = (n0 & 1023) + wn + ni * 16 + cl;
                    int bb = m >> 11, s = m & 2047;
                    int h = n >> 6, d = n & 63;
                    int bh = bb * 16 + h;
                    float c = acc[mi][ni][r];
                    short hi = f2bf(c);
                    if (region == 0) {
                        short lo = f2bf(c - bf2f(hi));
                        size_t base = ((size_t)bh * 2048 + s) * 128;
                        q2[base + d] = hi;
                        q2[base + 64 + d] = lo;
                    } else if (region == 1) {
                        short lo = f2bf(c - bf2f(hi));
                        size_t base = ((size_t)bh * 2048 + s) * 128;
                        k2[base + d] = hi;
                        k2[base + 64 + d] = lo;
                    } else {
                        vt[((size_t)bh * 64 + d) * 2048 + s] = hi;
                    }
                }
            }
        }
    }
}

// ---- Flash attention: grid (S/64, BH), 256 threads = 4 waves, each wave owns 16 q-rows.
// Q',K' = [bh][s][128] bf16 (hi d0..63 | lo d64..127). V^T = [bh][d][s] bf16.
// K/V tiles staged in LDS in MFMA-fragment order via global_load_lds (double-buffered,
// prefetch next tile before computing current; ONE barrier per iteration).
// Scores via split QK^T (6 MFMAs / 16x16 tile, two depth-3 chains). Online softmax.
// P->LDS->PV is per-wave (no barrier). Bias: per-head bf16 row staged in LDS.
__launch_bounds__(256)
__global__ void flash_kernel(const short* __restrict__ q2, const short* __restrict__ k2,
                             const short* __restrict__ vt, const short* __restrict__ btab,
                             short* __restrict__ attnb) {
    __shared__ __align__(16) short Ks[2][4096];   // [buf][(t*4+f)*64 + lane][8]
    __shared__ __align__(16) short Vs[2][2048];   // [buf][dt*64 + lane][8]
    __shared__ __align__(16) short Bsh[4096];     // bias row for this head (bf16)
    __shared__ __align__(16) short pbuf[4][16 * 40];  // per-wave P tile, stride 40
    const int tid = threadIdx.x;
    const int w = tid >> 6, l = tid & 63;
    const int rl = l >> 4, cl = l & 15;
    const int rl8 = rl * 8;
    const int bh = blockIdx.y;
    const int h = bh & 15;
    const int q0 = blockIdx.x * 64 + w * 16;

    const short* Q = q2 + (size_t)bh * Sc * 128;
    const short* Kp = k2 + (size_t)bh * Sc * 128;
    const short* V = vt + (size_t)bh * 64 * Sc;

    // bias row -> LDS (4096 bf16 = 8KB; 16 shorts per thread)
    {
        const short* src = btab + h * 4096 + tid * 16;
        *reinterpret_cast<s16x8*>(&Bsh[tid * 16]) = *reinterpret_cast<const s16x8*>(src);
        *reinterpret_cast<s16x8*>(&Bsh[tid * 16 + 8]) = *reinterpret_cast<const s16x8*>(src + 8);
    }

    // stage K/V tile for iteration it2 into buffer buf (3 global_load_lds per wave)
    auto stage = [&](int buf, int it2) {
        int kv0 = it2 * 32;
#pragma unroll
        for (int j = 0; j < 2; ++j) {
            int idx = w * 2 + j;          // 0..7 = (t<<2)|f
            int t = idx >> 2, f = idx & 3;
            const short* src =
                Kp + (size_t)(kv0 + t * 16 + cl) * 128 + (f >> 1) * 64 + (f & 1) * 32 + rl8;
            cp16(src, &Ks[buf][idx * 512]);
        }
        const short* vsrc = V + (size_t)(w * 16 + cl) * Sc + kv0 + rl8;
        cp16(vsrc, &Vs[buf][w * 512]);
    };

    // Q fragments (held in registers for the whole kernel)
    s16x8 qf[4];
#pragma unroll
    for (int sg = 0; sg < 2; ++sg)
#pragma unroll
        for (int a = 0; a < 2; ++a)
            qf[sg * 2 + a] =
                *reinterpret_cast<const s16x8*>(Q + (size_t)(q0 + cl) * 128 + sg * 64 + a * 32 + rl8);

    f32x4 acc[4];
#pragma unroll
    for (int i = 0; i < 4; ++i) acc[i] = (f32x4){0.f, 0.f, 0.f, 0.f};
    float mrow[4] = {-1e30f, -1e30f, -1e30f, -1e30f};
    float lrow[4] = {0.f, 0.f, 0.f, 0.f};

    stage(0, 0);
    __syncthreads();

    for (int it = 0; it < 64; ++it) {
        const int cur = it & 1;
        if (it + 1 < 64) stage(cur ^ 1, it + 1);  // prefetch overlaps this iteration's compute
        const int kv0 = it * 32;

        s16x8 kf[2][4], vf[4];
#pragma unroll
        for (int t = 0; t < 2; ++t)
#pragma unroll
            for (int f = 0; f < 4; ++f)
                kf[t][f] = *reinterpret_cast<const s16x8*>(&Ks[cur][((t * 4 + f) * 64 + l) * 8]);
#pragma unroll
        for (int dt = 0; dt < 4; ++dt)
            vf[dt] = *reinterpret_cast<const s16x8*>(&Vs[cur][(dt * 64 + l) * 8]);

        f32x4 sc[2];
#pragma unroll
        for (int t = 0; t < 2; ++t) {
            const f32x4 z = {0.f, 0.f, 0.f, 0.f};
            f32x4 sA = __builtin_amdgcn_mfma_f32_16x16x32_bf16(qf[0], kf[t][0], z, 0, 0, 0);
            sA = __builtin_amdgcn_mfma_f32_16x16x32_bf16(qf[1], kf[t][1], sA, 0, 0, 0);
            sA = __builtin_amdgcn_mfma_f32_16x16x32_bf16(qf[0], kf[t][2], sA, 0, 0, 0);
            f32x4 sB = __builtin_amdgcn_mfma_f32_16x16x32_bf16(qf[1], kf[t][3], z, 0, 0, 0);
            sB = __builtin_amdgcn_mfma_f32_16x16x32_bf16(qf[2], kf[t][0], sB, 0, 0, 0);
            sB = __builtin_amdgcn_mfma_f32_16x16x32_bf16(qf[3], kf[t][1], sB, 0, 0, 0);
            sc[t] = sA + sB;
            int col = kv0 + t * 16 + cl;
#pragma unroll
            for (int r = 0; r < 4; ++r)
                sc[t][r] += bf2f(Bsh[col - (q0 + rl * 4 + r) + 2047]);
        }

        float tm[4], al[4], pr[2][4], rs[4];
#pragma unroll
        for (int r = 0; r < 4; ++r) tm[r] = fmaxf(sc[0][r], sc[1][r]);
#pragma unroll
        for (int off = 1; off < 16; off <<= 1)
#pragma unroll
            for (int r = 0; r < 4; ++r) tm[r] = fmaxf(tm[r], __shfl_xor(tm[r], off));
#pragma unroll
        for (int r = 0; r < 4; ++r) {
            float mn = fmaxf(mrow[r], tm[r]);
            al[r] = __expf(mrow[r] - mn);
            mrow[r] = mn;
            pr[0][r] = __expf(sc[0][r] - mn);
            pr[1][r] = __expf(sc[1][r] - mn);
            rs[r] = pr[0][r] + pr[1][r];
        }
#pragma unroll
        for (int off = 1; off < 16; off <<= 1)
#pragma unroll
            for (int r = 0; r < 4; ++r) rs[r] += __shfl_xor(rs[r], off);
#pragma unroll
        for (int r = 0; r < 4; ++r) lrow[r] = lrow[r] * al[r] + rs[r];
#pragma unroll
        for (int i = 0; i < 4; ++i) {
            f32x4 t4 = acc[i];
#pragma unroll
            for (int r = 0; r < 4; ++r) t4[r] *= al[r];
            acc[i] = t4;
        }

        // P -> LDS (per-wave; wave-internal lgkmcnt ordering, no barrier needed)
        short* pl = &pbuf[w][0];
#pragma unroll
        for (int t = 0; t < 2; ++t)
#pragma unroll
            for (int r = 0; r < 4; ++r)
                pl[(rl * 4 + r) * 40 + t * 16 + cl] = f2bf(pr[t][r]);
        s16x8 pf = *reinterpret_cast<const s16x8*>(pl + cl * 40 + rl8);
#pragma unroll
        for (int dt = 0; dt < 4; ++dt)
            acc[dt] = __builtin_amdgcn_mfma_f32_16x16x32_bf16(pf, vf[dt], acc[dt], 0, 0, 0);

        __syncthreads();  // buf(cur) reads done; buf(cur^1) prefetch drained
    }

    int bb = bh >> 4;
#pragma unroll
    for (int dt = 0; dt < 4; ++dt)
#pragma unroll
        for (int r = 0; r < 4; ++r) {
            int q = q0 + rl * 4 + r;
            float o = acc[dt][r] / lrow[r];
            attnb[((size_t)(bb * 2048 + q)) * 1024 + h * 64 + dt * 16 + cl] = f2bf(o);
        }
}

extern "C" void kernel_launch(void* const* d_in, const int* in_sizes, int n_in,
                              void* d_out, int out_size, void* d_ws, size_t ws_size,
                              hipStream_t stream) {
    const float* X = (const float*)d_in[0];
    const float* Wq = (const float*)d_in[1];
    const float* Wk = (const float*)d_in[2];
    const float* Wv = (const float*)d_in[3];
    const float* Wo = (const float*)d_in[4];
    const float* RB = (const float*)d_in[5];

    // Workspace layout (~149 MB total)
    char* ws = (char*)d_ws;
    size_t off = 0;
    auto alloc = [&](size_t bytes) {
        void* p = ws + off;
        off += (bytes + 255) & ~(size_t)255;
        return p;
    };
    short* X2 = (short*)alloc((size_t)8192 * 2048 * 2);    // X hi|lo
    short* WT2 = (short*)alloc((size_t)3072 * 2048 * 2);   // [Wq;Wk;Wv]^T hi|lo
    short* q2 = (short*)alloc((size_t)64 * 2048 * 128 * 2);  // Q' hi|lo
    short* k2 = (short*)alloc((size_t)64 * 2048 * 128 * 2);  // K' hi|lo
    short* vt = (short*)alloc((size_t)64 * 64 * 2048 * 2);   // V^T
    short* attn = (short*)alloc((size_t)8192 * 1024 * 2);    // attention output bf16
    short* WoT = (short*)alloc((size_t)1024 * 1024 * 2);     // Wo^T
    short* btab = (short*)alloc((size_t)16 * 4096 * 2);      // bias table (bf16)

    xconv_kernel<<<8192, 256, 0, stream>>>(X, X2);
    wqkv_conv<<<dim3(32, 32, 3), dim3(32, 8), 0, stream>>>(Wq, Wk, Wv, WT2);
    wo_conv<<<dim3(32, 32), dim3(32, 8), 0, stream>>>(Wo, WoT);
    bias_kernel<<<256, 256, 0, stream>>>(RB, btab);
    // QKV projection: A=[Xhi|Xhi|Xlo] via aWrap, B=[Whi|Wlo|Whi] via bWrap, K'=3072
    gemm_bt<1><<<dim3(64, 24), 256, 0, stream>>>(X2, WT2, 3072, 2048, 2048, 1024, 2048,
                                                 nullptr, 0, q2, k2, vt);
    flash_kernel<<<dim3(32, 64), 256, 0, stream>>>(q2, k2, vt, btab, attn);
    // Output projection (single bf16)
    gemm_bt<0><<<dim3(64, 8), 256, 0, stream>>>(attn, WoT, 1024, 1024, 1024, 1 << 30, 1 << 30,
                                                (float*)d_out, 1024, nullptr, nullptr, nullptr);
}

// Round 3
// 542.728 us; speedup vs baseline: 1.7650x; 1.1671x over previous
//
#include <hip/hip_runtime.h>
#include <hip/hip_bf16.h>
#include <cstdint>

#define DI __device__ __forceinline__

typedef __attribute__((ext_vector_type(4))) float f32x4;
typedef __attribute__((ext_vector_type(8))) short s16x8;
typedef __attribute__((ext_vector_type(4))) short s16x4;
typedef unsigned int u32;

constexpr int Sc = 2048;
// B=4, D=1024, H=16, DK=64, M = B*S = 8192, BH = 64

DI short f2bf(float x) {
    __hip_bfloat16 h = __float2bfloat16(x);
    return __builtin_bit_cast(short, h);
}
DI float bf2f(short x) {
    __hip_bfloat16 h = __builtin_bit_cast(__hip_bfloat16, x);
    return __bfloat162float(h);
}

// async 16B global -> LDS (dest = wave-uniform base + lane*16)
DI void cp16(const short* g, short* l) {
    __builtin_amdgcn_global_load_lds(
        (const __attribute__((address_space(1))) u32*)g,
        (__attribute__((address_space(3))) u32*)l, 16, 0, 0);
}

// ---- X [8192][1024] f32 -> X2 [8192][2048] bf16 : cols [0,1024)=hi, [1024,2048)=lo
__global__ void xconv_kernel(const float* __restrict__ X, short* __restrict__ X2) {
    size_t i = ((size_t)blockIdx.x * 256 + threadIdx.x) * 4;
    float4 v = *reinterpret_cast<const float4*>(X + i);
    int m = (int)(i >> 10);
    int k = (int)(i & 1023);
    float vv[4] = {v.x, v.y, v.z, v.w};
    short hi[4], lo[4];
#pragma unroll
    for (int j = 0; j < 4; ++j) { hi[j] = f2bf(vv[j]); lo[j] = f2bf(vv[j] - bf2f(hi[j])); }
    s16x4 h4 = {hi[0], hi[1], hi[2], hi[3]};
    s16x4 l4 = {lo[0], lo[1], lo[2], lo[3]};
    *reinterpret_cast<s16x4*>(X2 + (size_t)m * 2048 + k) = h4;
    *reinterpret_cast<s16x4*>(X2 + (size_t)m * 2048 + 1024 + k) = l4;
}

// ---- Wq/Wk/Wv [1024][1024] f32 -> WT2 [3072][2048] bf16 (transposed; [n][k]: hi at k, lo at 1024+k)
__global__ void wqkv_conv(const float* __restrict__ Wq, const float* __restrict__ Wk,
                          const float* __restrict__ Wv, short* __restrict__ WT2) {
    __shared__ float t[32][33];
    int z = blockIdx.z;
    const float* W = (z == 0) ? Wq : (z == 1 ? Wk : Wv);
    int k0 = blockIdx.x * 32, n0 = blockIdx.y * 32;
    int tx = threadIdx.x, ty = threadIdx.y;
#pragma unroll
    for (int i = 0; i < 4; ++i)
        t[ty + 8 * i][tx] = W[(size_t)(k0 + ty + 8 * i) * 1024 + n0 + tx];
    __syncthreads();
#pragma unroll
    for (int i = 0; i < 4; ++i) {
        float v = t[tx][ty + 8 * i];
        short hi = f2bf(v), lo = f2bf(v - bf2f(hi));
        size_t r = (size_t)(z * 1024 + n0 + ty + 8 * i) * 2048 + k0 + tx;
        WT2[r] = hi;
        WT2[r + 1024] = lo;
    }
}

// ---- Wo [1024][1024] f32 -> WoT [1024][1024] bf16 (transposed, hi only)
__global__ void wo_conv(const float* __restrict__ Wo, short* __restrict__ WoT) {
    __shared__ float t[32][33];
    int k0 = blockIdx.x * 32, n0 = blockIdx.y * 32;
    int tx = threadIdx.x, ty = threadIdx.y;
#pragma unroll
    for (int i = 0; i < 4; ++i)
        t[ty + 8 * i][tx] = Wo[(size_t)(k0 + ty + 8 * i) * 1024 + n0 + tx];
    __syncthreads();
#pragma unroll
    for (int i = 0; i < 4; ++i)
        WoT[(size_t)(n0 + ty + 8 * i) * 1024 + k0 + tx] = f2bf(t[tx][ty + 8 * i]);
}

// ---- bias table [16][4096] bf16: tab[h][delta+2047] = rel_bias[bucket(delta)][h]
// Exact integer thresholds equivalent to int(log(rel/8)/log(16)*8) under correctly-rounded log.
__global__ void bias_kernel(const float* __restrict__ rel_bias, short* __restrict__ tab) {
    int idx = blockIdx.x * 256 + threadIdx.x;  // 16*4096
    int h = idx >> 12;
    int i = idx & 4095;
    int delta = i - 2047;
    int ad = delta < 0 ? -delta : delta;
    int b;
    if (ad < 8) b = ad;
    else if (ad < 12) b = 8;
    else if (ad < 16) b = 9;
    else if (ad < 23) b = 10;
    else if (ad < 32) b = 11;
    else if (ad < 46) b = 12;
    else if (ad < 64) b = 13;
    else if (ad < 91) b = 14;
    else b = 15;
    if (delta > 0) b += 16;
    tab[idx] = f2bf(rel_bias[b * 16 + h]);
}

// ---- GEMM: C[M,N] = A[M,K'] * B[K',N], B given as B^T [N][K'] bf16.
// global_load_lds staging (m97 structure: single LDS buffer, 2 barriers per K-step).
// Split-K' remap: colA = kk - (kk>=aWrap ? aWrap : 0), same for B.
// EPI=0: store fp32 C. EPI=1 (QKV): split-write Q'/K' (hi|lo) and V^T bf16.
template <int EPI>
__launch_bounds__(256)
__global__ void gemm_bt(const short* __restrict__ A, const short* __restrict__ Bt,
                        int K, int lda, int ldb, int aWrap, int bWrap,
                        float* __restrict__ C, int ldc,
                        short* __restrict__ q2, short* __restrict__ k2, short* __restrict__ vt) {
    __shared__ __align__(16) short As[128 * 32];
    __shared__ __align__(16) short Bs[128 * 32];
    const int tid = threadIdx.x;
    const int w = tid >> 6, l = tid & 63;
    const int m0 = blockIdx.x * 128, n0 = blockIdx.y * 128;
    const int wm = (w >> 1) * 64, wn = (w & 1) * 64;
    const int ar = tid >> 2, ac = (tid & 3) * 8;
    const int wb = w * 512;  // wave-uniform LDS base (shorts): lane writes at +l*8

    f32x4 acc[4][4];
#pragma unroll
    for (int i = 0; i < 4; ++i)
#pragma unroll
        for (int j = 0; j < 4; ++j) acc[i][j] = (f32x4){0.f, 0.f, 0.f, 0.f};

    const int nk = K / 32;
    for (int kt = 0; kt < nk; ++kt) {
        int kk = kt * 32;
        int ca = kk - (kk >= aWrap ? aWrap : 0);
        int cb = kk - (kk >= bWrap ? bWrap : 0);
        cp16(A + (size_t)(m0 + ar) * lda + ca + ac, As + wb);
        cp16(A + (size_t)(m0 + 64 + ar) * lda + ca + ac, As + 2048 + wb);
        cp16(Bt + (size_t)(n0 + ar) * ldb + cb + ac, Bs + wb);
        cp16(Bt + (size_t)(n0 + 64 + ar) * ldb + cb + ac, Bs + 2048 + wb);
        __syncthreads();  // own vmcnt(0) drained before barrier -> LDS tile ready
        s16x8 af[4], bfv[4];
#pragma unroll
        for (int i = 0; i < 4; ++i)
            af[i] = *reinterpret_cast<const s16x8*>(As + (wm + i * 16 + (l & 15)) * 32 + (l >> 4) * 8);
#pragma unroll
        for (int i = 0; i < 4; ++i)
            bfv[i] = *reinterpret_cast<const s16x8*>(Bs + (wn + i * 16 + (l & 15)) * 32 + (l >> 4) * 8);
#pragma unroll
        for (int mi = 0; mi < 4; ++mi)
#pragma unroll
            for (int ni = 0; ni < 4; ++ni)
                acc[mi][ni] = __builtin_amdgcn_mfma_f32_16x16x32_bf16(af[mi], bfv[ni], acc[mi][ni], 0, 0, 0);
        __syncthreads();  // all reads done before next tile's writes
    }

    const int rl = l >> 4, cl = l & 15;
    if (EPI == 0) {
#pragma unroll
        for (int mi = 0; mi < 4; ++mi) {
            int row = m0 + wm + mi * 16 + rl * 4;
#pragma unroll
            for (int ni = 0; ni < 4; ++ni) {
                int col = n0 + wn + ni * 16 + cl;
#pragma unroll
                for (int r = 0; r < 4; ++r)
                    C[(size_t)(row + r) * ldc + col] = acc[mi][ni][r];
            }
        }
    } else {
        int region = n0 >> 10;  // block-uniform: 0=Q 1=K 2=V
#pragma unroll
        for (int mi = 0; mi < 4; ++mi) {
#pragma unroll
            for (int ni = 0; ni < 4; ++ni) {
#pragma unroll
                for (int r = 0; r < 4; ++r) {
                    int m = m0 + wm + mi * 16 + rl * 4 + r;
                    int n = (n0 & 1023) + wn + ni * 16 + cl;
                    int bb = m >> 11, s = m & 2047;
                    int h = n >> 6, d = n & 63;
                    int bh = bb * 16 + h;
                    float c = acc[mi][ni][r];
                    short hi = f2bf(c);
                    if (region == 0) {
                        short lo = f2bf(c - bf2f(hi));
                        size_t base = ((size_t)bh * 2048 + s) * 128;
                        q2[base + d] = hi;
                        q2[base + 64 + d] = lo;
                    } else if (region == 1) {
                        short lo = f2bf(c - bf2f(hi));
                        size_t base = ((size_t)bh * 2048 + s) * 128;
                        k2[base + d] = hi;
                        k2[base + 64 + d] = lo;
                    } else {
                        vt[((size_t)bh * 64 + d) * 2048 + s] = hi;
                    }
                }
            }
        }
    }
}

// ---- Flash attention: grid (S/128, BH), 512 threads = 8 waves, each wave 16 q-rows.
// KVBLK=64. No online max (scores bounded ~|55|: exp(s) safe in fp32); per-lane partial
// row sums in registers, single cross-lane reduce at kernel end.
// K/V staged to LDS in MFMA-fragment order via global_load_lds, double-buffered.
// P->LDS->PV per-wave in two 32-col halves (no barrier).
__launch_bounds__(512, 4)
__global__ void flash_kernel(const short* __restrict__ q2, const short* __restrict__ k2,
                             const short* __restrict__ vt, const short* __restrict__ btab,
                             short* __restrict__ attnb) {
    __shared__ __align__(16) short Ks[2][8192];   // [buf][(t*4+f)*512 + l*8]
    __shared__ __align__(16) short Vs[2][4096];   // [buf][(dt*2+ks)*512 + l*8]
    __shared__ __align__(16) short Bsh[2176];     // bias slice for this block's q-range
    __shared__ __align__(16) short pbuf[8][16 * 34];  // per-wave P half-tile (16x32, stride 34)
    const int tid = threadIdx.x;
    const int w = tid >> 6, l = tid & 63;
    const int rl = l >> 4, cl = l & 15, rl8 = rl * 8;
    const int bh = blockIdx.y, h = bh & 15;
    const int q0b = blockIdx.x * 128;
    const int q0 = q0b + w * 16;

    const short* Q = q2 + (size_t)bh * Sc * 128;
    const short* Kp = k2 + (size_t)bh * Sc * 128;
    const short* V = vt + (size_t)bh * 64 * Sc;

    // bias slice: Bsh[i] = tab[delta+2047] for delta = col - (q0b + rowLocal), i = col - rowLocal + 127
    for (int i = tid; i < 2176; i += 512) Bsh[i] = btab[h * 4096 + (1920 - q0b) + i];

    auto stage = [&](int buf, int it2) {
        int kv0 = it2 * 64;
#pragma unroll
        for (int j = 0; j < 2; ++j) {
            int idx = w * 2 + j, t = idx >> 2, f = idx & 3;
            cp16(Kp + (size_t)(kv0 + t * 16 + cl) * 128 + (f >> 1) * 64 + (f & 1) * 32 + rl8,
                 &Ks[buf][idx * 512]);
        }
        cp16(V + (size_t)((w >> 1) * 16 + cl) * Sc + kv0 + (w & 1) * 32 + rl8,
             &Vs[buf][w * 512]);
    };

    // Q fragments in registers for whole kernel (A-operand: row=cl, k=rl8+j per 32-dim chunk)
    s16x8 qf[4];
#pragma unroll
    for (int sg = 0; sg < 2; ++sg)
#pragma unroll
        for (int a = 0; a < 2; ++a)
            qf[sg * 2 + a] =
                *reinterpret_cast<const s16x8*>(Q + (size_t)(q0 + cl) * 128 + sg * 64 + a * 32 + rl8);

    f32x4 acc[4];
#pragma unroll
    for (int i = 0; i < 4; ++i) acc[i] = (f32x4){0.f, 0.f, 0.f, 0.f};
    float psum[4] = {0.f, 0.f, 0.f, 0.f};

    stage(0, 0);
    __syncthreads();

    for (int it = 0; it < 32; ++it) {
        const int cur = it & 1;
        if (it + 1 < 32) stage(cur ^ 1, it + 1);  // prefetch overlaps compute; drained at barrier
        const int kv0 = it * 64;
        short* pl = &pbuf[w][0];
#pragma unroll
        for (int half = 0; half < 2; ++half) {
#pragma unroll
            for (int t2 = 0; t2 < 2; ++t2) {
                const int t = half * 2 + t2;
                const short* kb = &Ks[cur][t * 2048 + l * 8];
                s16x8 k0 = *reinterpret_cast<const s16x8*>(kb);
                s16x8 k1 = *reinterpret_cast<const s16x8*>(kb + 512);
                s16x8 kc = *reinterpret_cast<const s16x8*>(kb + 1024);
                s16x8 k3 = *reinterpret_cast<const s16x8*>(kb + 1536);
                const f32x4 z = {0.f, 0.f, 0.f, 0.f};
                f32x4 sA = __builtin_amdgcn_mfma_f32_16x16x32_bf16(qf[0], k0, z, 0, 0, 0);
                sA = __builtin_amdgcn_mfma_f32_16x16x32_bf16(qf[1], k1, sA, 0, 0, 0);
                sA = __builtin_amdgcn_mfma_f32_16x16x32_bf16(qf[0], kc, sA, 0, 0, 0);
                f32x4 sB = __builtin_amdgcn_mfma_f32_16x16x32_bf16(qf[1], k3, z, 0, 0, 0);
                sB = __builtin_amdgcn_mfma_f32_16x16x32_bf16(qf[2], k0, sB, 0, 0, 0);
                sB = __builtin_amdgcn_mfma_f32_16x16x32_bf16(qf[3], k1, sB, 0, 0, 0);
                f32x4 s4 = sA + sB;
                const int col = kv0 + t * 16 + cl;
                const int rowL = w * 16 + rl * 4;
#pragma unroll
                for (int r = 0; r < 4; ++r) {
                    float pv = __expf(s4[r] + bf2f(Bsh[col - (rowL + r) + 127]));
                    psum[r] += pv;
                    pl[(rl * 4 + r) * 34 + t2 * 16 + cl] = f2bf(pv);
                }
            }
            // PV for this 32-kv half (P read is per-wave; lgkm ordering suffices)
            s16x8 pf = *reinterpret_cast<const s16x8*>(pl + cl * 34 + rl8);
#pragma unroll
            for (int dt = 0; dt < 4; ++dt) {
                s16x8 vf = *reinterpret_cast<const s16x8*>(&Vs[cur][(dt * 2 + half) * 512 + l * 8]);
                acc[dt] = __builtin_amdgcn_mfma_f32_16x16x32_bf16(pf, vf, acc[dt], 0, 0, 0);
            }
        }
        __syncthreads();  // buf(cur) reads done; prefetch of buf(cur^1) drained
    }

    // single end-of-kernel row-sum reduce across the 16 cl lanes
#pragma unroll
    for (int off = 1; off < 16; off <<= 1)
#pragma unroll
        for (int r = 0; r < 4; ++r) psum[r] += __shfl_xor(psum[r], off);

    const int bb = bh >> 4;
#pragma unroll
    for (int dt = 0; dt < 4; ++dt)
#pragma unroll
        for (int r = 0; r < 4; ++r) {
            int q = q0 + rl * 4 + r;
            attnb[((size_t)(bb * 2048 + q)) * 1024 + h * 64 + dt * 16 + cl] =
                f2bf(acc[dt][r] / psum[r]);
        }
}

extern "C" void kernel_launch(void* const* d_in, const int* in_sizes, int n_in,
                              void* d_out, int out_size, void* d_ws, size_t ws_size,
                              hipStream_t stream) {
    const float* X = (const float*)d_in[0];
    const float* Wq = (const float*)d_in[1];
    const float* Wk = (const float*)d_in[2];
    const float* Wv = (const float*)d_in[3];
    const float* Wo = (const float*)d_in[4];
    const float* RB = (const float*)d_in[5];

    char* ws = (char*)d_ws;
    size_t off = 0;
    auto alloc = [&](size_t bytes) {
        void* p = ws + off;
        off += (bytes + 255) & ~(size_t)255;
        return p;
    };
    short* X2 = (short*)alloc((size_t)8192 * 2048 * 2);
    short* WT2 = (short*)alloc((size_t)3072 * 2048 * 2);
    short* q2 = (short*)alloc((size_t)64 * 2048 * 128 * 2);
    short* k2 = (short*)alloc((size_t)64 * 2048 * 128 * 2);
    short* vt = (short*)alloc((size_t)64 * 64 * 2048 * 2);
    short* attn = (short*)alloc((size_t)8192 * 1024 * 2);
    short* WoT = (short*)alloc((size_t)1024 * 1024 * 2);
    short* btab = (short*)alloc((size_t)16 * 4096 * 2);

    xconv_kernel<<<8192, 256, 0, stream>>>(X, X2);
    wqkv_conv<<<dim3(32, 32, 3), dim3(32, 8), 0, stream>>>(Wq, Wk, Wv, WT2);
    wo_conv<<<dim3(32, 32), dim3(32, 8), 0, stream>>>(Wo, WoT);
    bias_kernel<<<256, 256, 0, stream>>>(RB, btab);
    // QKV projection: A=[Xhi|Xhi|Xlo] via aWrap, B=[Whi|Wlo|Whi] via bWrap, K'=3072
    gemm_bt<1><<<dim3(64, 24), 256, 0, stream>>>(X2, WT2, 3072, 2048, 2048, 1024, 2048,
                                                 nullptr, 0, q2, k2, vt);
    flash_kernel<<<dim3(16, 64), 512, 0, stream>>>(q2, k2, vt, btab, attn);
    // Output projection (single bf16)
    gemm_bt<0><<<dim3(64, 8), 256, 0, stream>>>(attn, WoT, 1024, 1024, 1024, 1 << 30, 1 << 30,
                                                (float*)d_out, 1024, nullptr, nullptr, nullptr);
}

// Round 5
// 453.268 us; speedup vs baseline: 2.1133x; 1.1974x over previous
//
#include <hip/hip_runtime.h>
#include <hip/hip_bf16.h>
#include <cstdint>

#define DI __device__ __forceinline__

typedef __attribute__((ext_vector_type(4))) float f32x4;
typedef __attribute__((ext_vector_type(16))) float f32x16;
typedef __attribute__((ext_vector_type(8))) short s16x8;
typedef __attribute__((ext_vector_type(4))) short s16x4;
typedef __attribute__((ext_vector_type(4))) unsigned int u32x4;
typedef unsigned int u32;

constexpr int Sc = 2048;
constexpr float LOG2E = 1.44269504088896340736f;
// B=4, D=1024, H=16, DK=64, M = B*S = 8192, BH = 64

DI short f2bf(float x) {
    __hip_bfloat16 h = __float2bfloat16(x);
    return __builtin_bit_cast(short, h);
}
DI float bf2f(short x) {
    __hip_bfloat16 h = __builtin_bit_cast(__hip_bfloat16, x);
    return __bfloat162float(h);
}
// pack two f32 -> dword of 2 bf16 (lo = a, hi = b) via verified scalar converts
DI u32 pack2(float a, float b) {
    return (u32)(unsigned short)f2bf(a) | ((u32)(unsigned short)f2bf(b) << 16);
}

// async 16B global -> LDS (dest = wave-uniform base + lane*16)
DI void cp16(const short* g, short* l) {
    __builtin_amdgcn_global_load_lds(
        (const __attribute__((address_space(1))) u32*)g,
        (__attribute__((address_space(3))) u32*)l, 16, 0, 0);
}

DI float fexp2(float x) {
#if __has_builtin(__builtin_amdgcn_exp2f)
    return __builtin_amdgcn_exp2f(x);
#else
    return exp2f(x);
#endif
}
DI float frcp(float x) {
#if __has_builtin(__builtin_amdgcn_rcpf)
    return __builtin_amdgcn_rcpf(x);
#else
    return 1.0f / x;
#endif
}

// ---- X [8192][1024] f32 -> X2 [8192][2048] bf16 : cols [0,1024)=hi, [1024,2048)=lo
__global__ void xconv_kernel(const float* __restrict__ X, short* __restrict__ X2) {
    size_t i = ((size_t)blockIdx.x * 256 + threadIdx.x) * 4;
    float4 v = *reinterpret_cast<const float4*>(X + i);
    int m = (int)(i >> 10);
    int k = (int)(i & 1023);
    float vv[4] = {v.x, v.y, v.z, v.w};
    short hi[4], lo[4];
#pragma unroll
    for (int j = 0; j < 4; ++j) { hi[j] = f2bf(vv[j]); lo[j] = f2bf(vv[j] - bf2f(hi[j])); }
    s16x4 h4 = {hi[0], hi[1], hi[2], hi[3]};
    s16x4 l4 = {lo[0], lo[1], lo[2], lo[3]};
    *reinterpret_cast<s16x4*>(X2 + (size_t)m * 2048 + k) = h4;
    *reinterpret_cast<s16x4*>(X2 + (size_t)m * 2048 + 1024 + k) = l4;
}

// ---- Wq/Wk/Wv [1024][1024] f32 -> WT2 [3072][2048] bf16 (transposed; [n][k]: hi at k, lo at 1024+k)
__global__ void wqkv_conv(const float* __restrict__ Wq, const float* __restrict__ Wk,
                          const float* __restrict__ Wv, short* __restrict__ WT2) {
    __shared__ float t[32][33];
    int z = blockIdx.z;
    const float* W = (z == 0) ? Wq : (z == 1 ? Wk : Wv);
    int k0 = blockIdx.x * 32, n0 = blockIdx.y * 32;
    int tx = threadIdx.x, ty = threadIdx.y;
#pragma unroll
    for (int i = 0; i < 4; ++i)
        t[ty + 8 * i][tx] = W[(size_t)(k0 + ty + 8 * i) * 1024 + n0 + tx];
    __syncthreads();
#pragma unroll
    for (int i = 0; i < 4; ++i) {
        float v = t[tx][ty + 8 * i];
        short hi = f2bf(v), lo = f2bf(v - bf2f(hi));
        size_t r = (size_t)(z * 1024 + n0 + ty + 8 * i) * 2048 + k0 + tx;
        WT2[r] = hi;
        WT2[r + 1024] = lo;
    }
}

// ---- Wo [1024][1024] f32 -> WoT [1024][1024] bf16 (transposed, hi only)
__global__ void wo_conv(const float* __restrict__ Wo, short* __restrict__ WoT) {
    __shared__ float t[32][33];
    int k0 = blockIdx.x * 32, n0 = blockIdx.y * 32;
    int tx = threadIdx.x, ty = threadIdx.y;
#pragma unroll
    for (int i = 0; i < 4; ++i)
        t[ty + 8 * i][tx] = Wo[(size_t)(k0 + ty + 8 * i) * 1024 + n0 + tx];
    __syncthreads();
#pragma unroll
    for (int i = 0; i < 4; ++i)
        WoT[(size_t)(n0 + ty + 8 * i) * 1024 + k0 + tx] = f2bf(t[tx][ty + 8 * i]);
}

// ---- bias table [16][4096] bf16, PRE-SCALED by log2(e): tab[h][delta+2047] = log2e*rel_bias[bucket][h]
// Exact integer thresholds equivalent to int(log(rel/8)/log(16)*8) under correctly-rounded log.
__global__ void bias_kernel(const float* __restrict__ rel_bias, short* __restrict__ tab) {
    int idx = blockIdx.x * 256 + threadIdx.x;  // 16*4096
    int h = idx >> 12;
    int i = idx & 4095;
    int delta = i - 2047;
    int ad = delta < 0 ? -delta : delta;
    int b;
    if (ad < 8) b = ad;
    else if (ad < 12) b = 8;
    else if (ad < 16) b = 9;
    else if (ad < 23) b = 10;
    else if (ad < 32) b = 11;
    else if (ad < 46) b = 12;
    else if (ad < 64) b = 13;
    else if (ad < 91) b = 14;
    else b = 15;
    if (delta > 0) b += 16;
    tab[idx] = f2bf(rel_bias[b * 16 + h] * LOG2E);
}

// ---- GEMM: C[M,N] = A[M,K'] * B[K',N], B given as B^T [N][K'] bf16.
// global_load_lds staging (m97 structure). Split-K' remap via aWrap/bWrap.
// EPI=0: store fp32 C. EPI=1 (QKV): Q scaled by log2e + split hi/lo; K split; V^T bf16.
template <int EPI>
__launch_bounds__(256)
__global__ void gemm_bt(const short* __restrict__ A, const short* __restrict__ Bt,
                        int K, int lda, int ldb, int aWrap, int bWrap,
                        float* __restrict__ C, int ldc,
                        short* __restrict__ q2, short* __restrict__ k2, short* __restrict__ vt) {
    __shared__ __align__(16) short As[128 * 32];
    __shared__ __align__(16) short Bs[128 * 32];
    const int tid = threadIdx.x;
    const int w = tid >> 6, l = tid & 63;
    const int m0 = blockIdx.x * 128, n0 = blockIdx.y * 128;
    const int wm = (w >> 1) * 64, wn = (w & 1) * 64;
    const int ar = tid >> 2, ac = (tid & 3) * 8;
    const int wb = w * 512;

    f32x4 acc[4][4];
#pragma unroll
    for (int i = 0; i < 4; ++i)
#pragma unroll
        for (int j = 0; j < 4; ++j) acc[i][j] = (f32x4){0.f, 0.f, 0.f, 0.f};

    const int nk = K / 32;
    for (int kt = 0; kt < nk; ++kt) {
        int kk = kt * 32;
        int ca = kk - (kk >= aWrap ? aWrap : 0);
        int cb = kk - (kk >= bWrap ? bWrap : 0);
        cp16(A + (size_t)(m0 + ar) * lda + ca + ac, As + wb);
        cp16(A + (size_t)(m0 + 64 + ar) * lda + ca + ac, As + 2048 + wb);
        cp16(Bt + (size_t)(n0 + ar) * ldb + cb + ac, Bs + wb);
        cp16(Bt + (size_t)(n0 + 64 + ar) * ldb + cb + ac, Bs + 2048 + wb);
        __syncthreads();
        s16x8 af[4], bfv[4];
#pragma unroll
        for (int i = 0; i < 4; ++i)
            af[i] = *reinterpret_cast<const s16x8*>(As + (wm + i * 16 + (l & 15)) * 32 + (l >> 4) * 8);
#pragma unroll
        for (int i = 0; i < 4; ++i)
            bfv[i] = *reinterpret_cast<const s16x8*>(Bs + (wn + i * 16 + (l & 15)) * 32 + (l >> 4) * 8);
#pragma unroll
        for (int mi = 0; mi < 4; ++mi)
#pragma unroll
            for (int ni = 0; ni < 4; ++ni)
                acc[mi][ni] = __builtin_amdgcn_mfma_f32_16x16x32_bf16(af[mi], bfv[ni], acc[mi][ni], 0, 0, 0);
        __syncthreads();
    }

    const int rl = l >> 4, cl = l & 15;
    if (EPI == 0) {
#pragma unroll
        for (int mi = 0; mi < 4; ++mi) {
            int row = m0 + wm + mi * 16 + rl * 4;
#pragma unroll
            for (int ni = 0; ni < 4; ++ni) {
                int col = n0 + wn + ni * 16 + cl;
#pragma unroll
                for (int r = 0; r < 4; ++r)
                    C[(size_t)(row + r) * ldc + col] = acc[mi][ni][r];
            }
        }
    } else {
        int region = n0 >> 10;  // block-uniform: 0=Q 1=K 2=V
#pragma unroll
        for (int mi = 0; mi < 4; ++mi) {
#pragma unroll
            for (int ni = 0; ni < 4; ++ni) {
#pragma unroll
                for (int r = 0; r < 4; ++r) {
                    int m = m0 + wm + mi * 16 + rl * 4 + r;
                    int n = (n0 & 1023) + wn + ni * 16 + cl;
                    int bb = m >> 11, s = m & 2047;
                    int h = n >> 6, d = n & 63;
                    int bh = bb * 16 + h;
                    float c = acc[mi][ni][r];
                    if (region == 0) {
                        c *= LOG2E;  // fold softmax base-2 conversion into Q
                        short hi = f2bf(c);
                        short lo = f2bf(c - bf2f(hi));
                        size_t base = ((size_t)bh * 2048 + s) * 128;
                        q2[base + d] = hi;
                        q2[base + 64 + d] = lo;
                    } else if (region == 1) {
                        short hi = f2bf(c);
                        short lo = f2bf(c - bf2f(hi));
                        size_t base = ((size_t)bh * 2048 + s) * 128;
                        k2[base + d] = hi;
                        k2[base + 64 + d] = lo;
                    } else {
                        vt[((size_t)bh * 64 + d) * 2048 + s] = f2bf(c);
                    }
                }
            }
        }
    }
}

// ---- Flash attention, 32x32 swapped-operand form.
// Grid: 512 blocks (XCD-swizzled), 512 threads = 8 waves; wave owns 32 q-rows (q-block 256).
// Swapped QK: mfma(A=K', B=Q') -> lane holds 16 scores of ONE q-row (q = lane&31).
// P stays in registers; cross-half exchange via verified __shfl_xor(32) + select.
// No online max (|score*log2e| < ~90 << 127, exp2/fp32-sum safe); psum is in-lane scalar.
// K tile [64][128] and V^T tile [64][64] staged via global_load_lds with XOR-swizzled
// global source (linear LDS dest), double-buffered, one barrier per iteration.
__launch_bounds__(512, 4)
__global__ void flash_kernel(const short* __restrict__ q2, const short* __restrict__ k2,
                             const short* __restrict__ vt, const short* __restrict__ btab,
                             short* __restrict__ attnb) {
    __shared__ __align__(16) short Ks[2][8192];   // [buf] 64 rows x 16 chunks(16B), slot = c ^ (r&15)
    __shared__ __align__(16) short Vs[2][4096];   // [buf] 64 d-rows x 8 chunks, slot = c ^ (d&7)
    __shared__ __align__(16) short Bsh[2304];     // bias slice (bf16, log2e-scaled)

    const int tid = threadIdx.x;
    const int w = tid >> 6, l = tid & 63;
    const int l31 = l & 31, hi = l >> 5;

    // XCD swizzle: all 8 q-blocks of one bh land on one XCD (L % 8 == bh % 8)
    const int L = blockIdx.x;
    const int xcd = L & 7, idx = L >> 3;
    const int bh = xcd + 8 * (idx & 7);
    const int qb = idx >> 3;
    const int h = bh & 15;
    const int q0b = qb * 256;
    const int qw0 = q0b + w * 32;
    const int qL = w * 32 + l31;

    const short* Q = q2 + (size_t)bh * Sc * 128;
    const short* Kp = k2 + (size_t)bh * Sc * 128;
    const short* V = vt + (size_t)bh * 64 * Sc;

    {
        int base = h * 4096 + 1792 - q0b;
        for (int i = tid; i < 2304; i += 512) Bsh[i] = btab[base + i];
    }

    auto stage = [&](int buf, int it2) {
        int kv0 = it2 * 64;
#pragma unroll
        for (int j = 0; j < 2; ++j) {
            int o = w * 128 + j * 64 + l;          // K chunk index 0..1023
            int r = o >> 4, cs = o & 15;
            int cg = cs ^ (r & 15);                // inverse swizzle on global source
            cp16(Kp + (size_t)(kv0 + r) * 128 + cg * 8, &Ks[buf][(w * 128 + j * 64) * 8]);
        }
        {
            int o = w * 64 + l;                    // V chunk index 0..511
            int d = o >> 3, cs = o & 7;
            int cg = cs ^ (d & 7);
            cp16(V + (size_t)d * 2048 + kv0 + cg * 8, &Vs[buf][(w * 64) * 8]);
        }
    };

    // Q B-frags (8 chunks: c=0..3 hi-part d0..63, c=4..7 lo-part), resident whole kernel
    s16x8 qf[8];
#pragma unroll
    for (int c = 0; c < 8; ++c)
        qf[c] = *reinterpret_cast<const s16x8*>(Q + (size_t)(qw0 + l31) * 128 + c * 16 + hi * 8);

    f32x16 accO[2];
#pragma unroll
    for (int i = 0; i < 16; ++i) { accO[0][i] = 0.f; accO[1][i] = 0.f; }
    float psum = 0.f;

    stage(0, 0);
    __syncthreads();

    for (int it = 0; it < 32; ++it) {
        const int cur = it & 1;
        if (it + 1 < 32) stage(cur ^ 1, it + 1);
        const int kv0 = it * 64;
#pragma unroll
        for (int T = 0; T < 2; ++T) {  // two 32-kv tiles
            const int rA = T * 32 + l31;
            const int rsw = rA & 15;
            const short* kbase = &Ks[cur][rA * 128];
            s16x8 kh[4];
#pragma unroll
            for (int c = 0; c < 4; ++c)
                kh[c] = *reinterpret_cast<const s16x8*>(kbase + ((c * 2 + hi) ^ rsw) * 8);
            f32x16 acc = {0.f,0.f,0.f,0.f,0.f,0.f,0.f,0.f,0.f,0.f,0.f,0.f,0.f,0.f,0.f,0.f};
#pragma unroll
            for (int c = 0; c < 4; ++c)  // Khi . Qhi
                acc = __builtin_amdgcn_mfma_f32_32x32x16_bf16(kh[c], qf[c], acc, 0, 0, 0);
#pragma unroll
            for (int c = 0; c < 4; ++c)  // Khi . Qlo
                acc = __builtin_amdgcn_mfma_f32_32x32x16_bf16(kh[c], qf[c + 4], acc, 0, 0, 0);
#pragma unroll
            for (int c = 0; c < 4; ++c) {  // Klo . Qhi
                s16x8 klo = *reinterpret_cast<const s16x8*>(kbase + (((c + 4) * 2 + hi) ^ rsw) * 8);
                acc = __builtin_amdgcn_mfma_f32_32x32x16_bf16(klo, qf[c], acc, 0, 0, 0);
            }
            // softmax (base-2, no max) + P-frag build + PV, per 16-kv subtile
#pragma unroll
            for (int t2 = 0; t2 < 2; ++t2) {
                u32 pk[4];
#pragma unroll
                for (int i = 0; i < 4; ++i) {
                    const int ii = t2 * 4 + i;                       // pair index
                    const int pstart = ((ii & 1) * 2) + ((ii >> 1) * 8);
                    const int kvg = kv0 + T * 32 + pstart + 4 * hi;  // pair-start kv (even)
                    const int i0 = kvg - qL + 255;
                    const float b0 = bf2f(Bsh[i0]);
                    const float b1 = bf2f(Bsh[i0 + 1]);
                    const int r0 = t2 * 8 + i * 2;
                    const float e0 = fexp2(acc[r0] + b0);
                    const float e1 = fexp2(acc[r0 + 1] + b1);
                    psum += e0 + e1;
                    pk[i] = pack2(e0, e1);
                }
                // cross-half exchange: lane(hi=0) needs partner's pk[0..1] as dwords 2..3,
                // lane(hi=1) needs partner's pk[2..3] as dwords 0..1.
                const u32 ex0 = __shfl_xor(pk[0], 32);
                const u32 ex1 = __shfl_xor(pk[1], 32);
                const u32 ex2 = __shfl_xor(pk[2], 32);
                const u32 ex3 = __shfl_xor(pk[3], 32);
                const u32 d0 = hi ? ex2 : pk[0];
                const u32 d1 = hi ? ex3 : pk[1];
                const u32 d2 = hi ? pk[2] : ex0;
                const u32 d3 = hi ? pk[3] : ex1;
                u32x4 pv4 = {d0, d1, d2, d3};
                s16x8 pfrag = __builtin_bit_cast(s16x8, pv4);
                const int tg = T * 2 + t2;
#pragma unroll
                for (int dt = 0; dt < 2; ++dt) {
                    const int d = dt * 32 + l31;
                    s16x8 vf = *reinterpret_cast<const s16x8*>(
                        &Vs[cur][d * 64 + ((tg * 2 + hi) ^ (d & 7)) * 8]);
                    accO[dt] = __builtin_amdgcn_mfma_f32_32x32x16_bf16(pfrag, vf, accO[dt], 0, 0, 0);
                }
            }
        }
        __syncthreads();
    }

    // combine the two half-wave partial sums (lanes l and l^32 share q = l&31)
    psum += __shfl_xor(psum, 32);

    const int bb = bh >> 4;
#pragma unroll
    for (int r = 0; r < 16; ++r) {
        const int qloc = (r & 3) + 8 * (r >> 2) + 4 * hi;
        const float inv = frcp(__shfl(psum, qloc));
        const size_t rowbase = ((size_t)(bb * 2048 + qw0 + qloc)) * 1024 + h * 64;
#pragma unroll
        for (int dt = 0; dt < 2; ++dt)
            attnb[rowbase + dt * 32 + l31] = f2bf(accO[dt][r] * inv);
    }
}

extern "C" void kernel_launch(void* const* d_in, const int* in_sizes, int n_in,
                              void* d_out, int out_size, void* d_ws, size_t ws_size,
                              hipStream_t stream) {
    const float* X = (const float*)d_in[0];
    const float* Wq = (const float*)d_in[1];
    const float* Wk = (const float*)d_in[2];
    const float* Wv = (const float*)d_in[3];
    const float* Wo = (const float*)d_in[4];
    const float* RB = (const float*)d_in[5];

    char* ws = (char*)d_ws;
    size_t off = 0;
    auto alloc = [&](size_t bytes) {
        void* p = ws + off;
        off += (bytes + 255) & ~(size_t)255;
        return p;
    };
    short* X2 = (short*)alloc((size_t)8192 * 2048 * 2);
    short* WT2 = (short*)alloc((size_t)3072 * 2048 * 2);
    short* q2 = (short*)alloc((size_t)64 * 2048 * 128 * 2);
    short* k2 = (short*)alloc((size_t)64 * 2048 * 128 * 2);
    short* vt = (short*)alloc((size_t)64 * 64 * 2048 * 2);
    short* attn = (short*)alloc((size_t)8192 * 1024 * 2);
    short* WoT = (short*)alloc((size_t)1024 * 1024 * 2);
    short* btab = (short*)alloc((size_t)16 * 4096 * 2);

    xconv_kernel<<<8192, 256, 0, stream>>>(X, X2);
    wqkv_conv<<<dim3(32, 32, 3), dim3(32, 8), 0, stream>>>(Wq, Wk, Wv, WT2);
    wo_conv<<<dim3(32, 32), dim3(32, 8), 0, stream>>>(Wo, WoT);
    bias_kernel<<<256, 256, 0, stream>>>(RB, btab);
    // QKV projection: A=[Xhi|Xhi|Xlo] via aWrap, B=[Whi|Wlo|Whi] via bWrap, K'=3072
    gemm_bt<1><<<dim3(64, 24), 256, 0, stream>>>(X2, WT2, 3072, 2048, 2048, 1024, 2048,
                                                 nullptr, 0, q2, k2, vt);
    flash_kernel<<<512, 512, 0, stream>>>(q2, k2, vt, btab, attn);
    // Output projection (single bf16)
    gemm_bt<0><<<dim3(64, 8), 256, 0, stream>>>(attn, WoT, 1024, 1024, 1024, 1 << 30, 1 << 30,
                                                (float*)d_out, 1024, nullptr, nullptr, nullptr);
}